// Round 7
// baseline (292.452 us; speedup 1.0000x reference)
//
#include <hip/hip_runtime.h>

#define NN 50000
#define DIM 64
#define NE 1250000
#define NPARTS 196  // ceil(50000/256)

// threads for the unrolled edge kernels: 512 blocks * 256 thr * U=10 edges >= NE
#define EBLOCKS 512
#define ETHREADS (EBLOCKS * 256)
#define U 10

// ---------------- degree count (10-deep MLP batches) ----------------
__global__ __launch_bounds__(256) void k_count(const int* __restrict__ row,
                                               int* __restrict__ deg) {
    int tid = blockIdx.x * blockDim.x + threadIdx.x;
    int r[U];
#pragma unroll
    for (int k = 0; k < U; ++k) {
        int e = tid + k * ETHREADS;
        r[k] = (e < NE) ? row[e] : -1;  // 10 independent loads in flight
    }
#pragma unroll
    for (int k = 0; k < U; ++k)
        if (r[k] >= 0) atomicAdd(&deg[r[k]], 1);  // 10 independent atomics
}

// ---------------- hierarchical exclusive scan over deg -> offs ----------------
__global__ __launch_bounds__(256) void k_scan_part(const int* __restrict__ deg,
                                                   int* __restrict__ partial) {
    __shared__ int s[256];
    int t = threadIdx.x;
    int i = blockIdx.x * 256 + t;
    s[t] = (i < NN) ? deg[i] : 0;
    __syncthreads();
    for (int off = 128; off > 0; off >>= 1) {
        if (t < off) s[t] += s[t + off];
        __syncthreads();
    }
    if (t == 0) partial[blockIdx.x] = s[0];
}

__global__ __launch_bounds__(256) void k_scan_top(int* __restrict__ partial) {
    __shared__ int s[256];
    int t = threadIdx.x;
    int v = (t < NPARTS) ? partial[t] : 0;
    s[t] = v;
    __syncthreads();
    for (int off = 1; off < 256; off <<= 1) {
        int x = (t >= off) ? s[t - off] : 0;
        __syncthreads();
        s[t] += x;
        __syncthreads();
    }
    if (t < NPARTS) partial[t] = s[t] - v;  // exclusive block offsets
}

__global__ __launch_bounds__(256) void k_scan_final(const int* __restrict__ deg,
                                                    const int* __restrict__ partial,
                                                    int* __restrict__ offs) {
    __shared__ int s[256];
    int t = threadIdx.x;
    int i = blockIdx.x * 256 + t;
    int v = (i < NN) ? deg[i] : 0;
    s[t] = v;
    __syncthreads();
    for (int off = 1; off < 256; off <<= 1) {
        int x = (t >= off) ? s[t - off] : 0;
        __syncthreads();
        s[t] += x;
        __syncthreads();
    }
    int excl = s[t] - v;
    if (i <= NN) offs[i] = partial[blockIdx.x] + excl;  // offs[NN] = NE (total)
}

// ---------------- CSR fill (10-deep MLP batches per phase) ----------------
__global__ __launch_bounds__(256) void k_fill(const int* __restrict__ row,
                                              const int* __restrict__ col,
                                              const int* __restrict__ offs,
                                              int* __restrict__ cursor,
                                              int* __restrict__ csr) {
    int tid = blockIdx.x * blockDim.x + threadIdx.x;
    int r[U], c[U], base[U], pos[U];
#pragma unroll
    for (int k = 0; k < U; ++k) {
        int e = tid + k * ETHREADS;
        bool ok = (e < NE);
        r[k] = ok ? row[e] : -1;  // 10 independent loads
        c[k] = ok ? col[e] : 0;
    }
#pragma unroll
    for (int k = 0; k < U; ++k)
        base[k] = (r[k] >= 0) ? offs[r[k]] : 0;  // 10 independent random loads
#pragma unroll
    for (int k = 0; k < U; ++k)
        pos[k] = (r[k] >= 0) ? atomicAdd(&cursor[r[k]], 1) : 0;  // 10 independent atomics
#pragma unroll
    for (int k = 0; k < U; ++k)
        if (r[k] >= 0) csr[base[k] + pos[k]] = c[k];  // 10 independent stores
}

// ---------------- one propagation layer ----------------
// x_new[r] = (1/deg[r]) * sum_{e in CSR[r]} x[col[e]]
// one 64-lane wave per node, lane = feature dim, 8-wide MLP unroll.
// FIRST layer also initializes out = 0.25*(x0 + x1).
template <bool FIRST>
__global__ __launch_bounds__(256) void k_layer(const float* __restrict__ xin,
                                               float* __restrict__ xout,
                                               float* __restrict__ out,
                                               const int* __restrict__ offs,
                                               const int* __restrict__ csr) {
    int wave = (blockIdx.x * blockDim.x + threadIdx.x) >> 6;
    int lane = threadIdx.x & 63;
    if (wave >= NN) return;
    int beg = offs[wave];
    int end = offs[wave + 1];
    const float* xl = xin + lane;

    float a0 = 0.f, a1 = 0.f, a2 = 0.f, a3 = 0.f;
    int e = beg;
    for (; e + 8 <= end; e += 8) {
        int c0 = csr[e + 0], c1 = csr[e + 1], c2 = csr[e + 2], c3 = csr[e + 3];
        int c4 = csr[e + 4], c5 = csr[e + 5], c6 = csr[e + 6], c7 = csr[e + 7];
        float v0 = xl[c0 * DIM];
        float v1 = xl[c1 * DIM];
        float v2 = xl[c2 * DIM];
        float v3 = xl[c3 * DIM];
        float v4 = xl[c4 * DIM];
        float v5 = xl[c5 * DIM];
        float v6 = xl[c6 * DIM];
        float v7 = xl[c7 * DIM];
        a0 += v0 + v4;
        a1 += v1 + v5;
        a2 += v2 + v6;
        a3 += v3 + v7;
    }
    for (; e < end; ++e) a0 += xl[csr[e] * DIM];

    float acc = (a0 + a1) + (a2 + a3);
    int d = end - beg;
    float v = (d > 0) ? acc / (float)d : 0.0f;

    int o = wave * DIM + lane;
    xout[o] = v;
    if (FIRST)
        out[o] = 0.25f * (xin[o] + v);  // xin == emb here: folds k_init_out
    else
        out[o] += 0.25f * v;
}

extern "C" void kernel_launch(void* const* d_in, const int* in_sizes, int n_in,
                              void* d_out, int out_size, void* d_ws, size_t ws_size,
                              hipStream_t stream) {
    const int* edge = (const int*)d_in[0];
    const int* row = edge;        // edge_index[0]
    const int* col = edge + NE;   // edge_index[1]
    const float* emb = (const float*)d_in[1];
    float* out = (float*)d_out;

    // workspace layout (ints, 64-aligned chunks)
    int* deg    = (int*)d_ws;          // 50000 (padded 50048)
    int* cursor = deg + 50048;         // 50000 (padded 50048)
    int* offs   = cursor + 50048;      // 50001 (padded 50112)
    int* partial= offs + 50112;        // 256
    int* csr    = partial + 256;       // 1250000 (padded 1250048)
    float* xa   = (float*)(csr + 1250048);  // 3.2M floats
    float* xb   = xa + NN * DIM;            // 3.2M floats
    // total ~31.2 MB

    hipMemsetAsync(deg, 0, (50048 + 50048) * sizeof(int), stream);  // deg + cursor

    k_count     <<<EBLOCKS, 256, 0, stream>>>(row, deg);
    k_scan_part <<<NPARTS, 256, 0, stream>>>(deg, partial);
    k_scan_top  <<<1, 256, 0, stream>>>(partial);
    k_scan_final<<<NPARTS, 256, 0, stream>>>(deg, partial, offs);
    k_fill      <<<EBLOCKS, 256, 0, stream>>>(row, col, offs, cursor, csr);

    int layer_blocks = (NN * 64) / 256;  // 12500
    k_layer<true> <<<layer_blocks, 256, 0, stream>>>(emb, xa, out, offs, csr);
    k_layer<false><<<layer_blocks, 256, 0, stream>>>(xa,  xb, out, offs, csr);
    k_layer<false><<<layer_blocks, 256, 0, stream>>>(xb,  xa, out, offs, csr);
}

// Round 8
// 273.623 us; speedup vs baseline: 1.0688x; 1.0688x over previous
//
#include <hip/hip_runtime.h>

#define NN 50000
#define DIM 64
#define NE 1250000
#define NPARTS 196  // ceil(50000/256)

// ---- k_count config: 1280 blocks * 256 thr * U=4 = 1.31M slots >= NE,
//      keeps occupancy high (20 waves/CU) AND 4-deep MLP per thread.
#define CBLOCKS 1280
#define CTHREADS (CBLOCKS * 256)
#define CU 4

// ---- k_fill config: 256 edge-slices x 8 row-ranges = 2048 blocks.
//      block b: slice b>>3, row-range b&7. With round-robin blockIdx->XCD,
//      each csr line is written by exactly one XCD -> full-line evictions.
#define NSLICES 256
#define SLICE 4883            // ceil(NE / NSLICES)
#define RANGE 6250            // NN / 8 rows per XCD

// ---------------- degree count ----------------
__global__ __launch_bounds__(256) void k_count(const int* __restrict__ row,
                                               int* __restrict__ deg) {
    int tid = blockIdx.x * blockDim.x + threadIdx.x;
    int r[CU];
#pragma unroll
    for (int k = 0; k < CU; ++k) {
        int e = tid + k * CTHREADS;
        r[k] = (e < NE) ? row[e] : -1;  // 4 independent loads in flight
    }
#pragma unroll
    for (int k = 0; k < CU; ++k)
        if (r[k] >= 0) atomicAdd(&deg[r[k]], 1);  // 4 independent atomics
}

// ---------------- hierarchical exclusive scan over deg -> offs ----------------
__global__ __launch_bounds__(256) void k_scan_part(const int* __restrict__ deg,
                                                   int* __restrict__ partial) {
    __shared__ int s[256];
    int t = threadIdx.x;
    int i = blockIdx.x * 256 + t;
    s[t] = (i < NN) ? deg[i] : 0;
    __syncthreads();
    for (int off = 128; off > 0; off >>= 1) {
        if (t < off) s[t] += s[t + off];
        __syncthreads();
    }
    if (t == 0) partial[blockIdx.x] = s[0];
}

__global__ __launch_bounds__(256) void k_scan_top(int* __restrict__ partial) {
    __shared__ int s[256];
    int t = threadIdx.x;
    int v = (t < NPARTS) ? partial[t] : 0;
    s[t] = v;
    __syncthreads();
    for (int off = 1; off < 256; off <<= 1) {
        int x = (t >= off) ? s[t - off] : 0;
        __syncthreads();
        s[t] += x;
        __syncthreads();
    }
    if (t < NPARTS) partial[t] = s[t] - v;  // exclusive block offsets
}

__global__ __launch_bounds__(256) void k_scan_final(const int* __restrict__ deg,
                                                    const int* __restrict__ partial,
                                                    int* __restrict__ offs) {
    __shared__ int s[256];
    int t = threadIdx.x;
    int i = blockIdx.x * 256 + t;
    int v = (i < NN) ? deg[i] : 0;
    s[t] = v;
    __syncthreads();
    for (int off = 1; off < 256; off <<= 1) {
        int x = (t >= off) ? s[t - off] : 0;
        __syncthreads();
        s[t] += x;
        __syncthreads();
    }
    int excl = s[t] - v;
    if (i <= NN) offs[i] = partial[blockIdx.x] + excl;  // offs[NN] = NE (total)
}

// ---------------- CSR fill, XCD-partitioned by row range ----------------
// block b: edges [ (b>>3)*SLICE, ... ), rows [ (b&7)*RANGE, (b&7+1)*RANGE ).
// Every (slice, range) pair covered exactly once -> correct regardless of
// XCD mapping; with blockIdx%8 == XCD, csr lines are single-XCD-written,
// eliminating the 17x partial-line write amplification seen in r4/r7.
__global__ __launch_bounds__(256) void k_fill(const int* __restrict__ row,
                                              const int* __restrict__ col,
                                              const int* __restrict__ offs,
                                              int* __restrict__ cursor,
                                              int* __restrict__ csr) {
    int slice = blockIdx.x >> 3;
    int lo = (blockIdx.x & 7) * RANGE;
    int hi = lo + RANGE;
    int beg = slice * SLICE;
    int end = beg + SLICE;
    if (end > NE) end = NE;
    for (int e = beg + threadIdx.x; e < end; e += 256) {
        int r = row[e];
        if (r >= lo && r < hi) {
            int pos = offs[r] + atomicAdd(&cursor[r], 1);
            csr[pos] = col[e];
        }
    }
}

// ---------------- one propagation layer ----------------
// x_new[r] = (1/deg[r]) * sum_{e in CSR[r]} x[col[e]]
// one 64-lane wave per node, lane = feature dim, 8-wide MLP unroll.
// FIRST layer also initializes out = 0.25*(x0 + x1).
template <bool FIRST>
__global__ __launch_bounds__(256) void k_layer(const float* __restrict__ xin,
                                               float* __restrict__ xout,
                                               float* __restrict__ out,
                                               const int* __restrict__ offs,
                                               const int* __restrict__ csr) {
    int wave = (blockIdx.x * blockDim.x + threadIdx.x) >> 6;
    int lane = threadIdx.x & 63;
    if (wave >= NN) return;
    int beg = offs[wave];
    int end = offs[wave + 1];
    const float* xl = xin + lane;

    float a0 = 0.f, a1 = 0.f, a2 = 0.f, a3 = 0.f;
    int e = beg;
    for (; e + 8 <= end; e += 8) {
        int c0 = csr[e + 0], c1 = csr[e + 1], c2 = csr[e + 2], c3 = csr[e + 3];
        int c4 = csr[e + 4], c5 = csr[e + 5], c6 = csr[e + 6], c7 = csr[e + 7];
        float v0 = xl[c0 * DIM];
        float v1 = xl[c1 * DIM];
        float v2 = xl[c2 * DIM];
        float v3 = xl[c3 * DIM];
        float v4 = xl[c4 * DIM];
        float v5 = xl[c5 * DIM];
        float v6 = xl[c6 * DIM];
        float v7 = xl[c7 * DIM];
        a0 += v0 + v4;
        a1 += v1 + v5;
        a2 += v2 + v6;
        a3 += v3 + v7;
    }
    for (; e < end; ++e) a0 += xl[csr[e] * DIM];

    float acc = (a0 + a1) + (a2 + a3);
    int d = end - beg;
    float v = (d > 0) ? acc / (float)d : 0.0f;

    int o = wave * DIM + lane;
    xout[o] = v;
    if (FIRST)
        out[o] = 0.25f * (xin[o] + v);  // xin == emb here: folds k_init_out
    else
        out[o] += 0.25f * v;
}

extern "C" void kernel_launch(void* const* d_in, const int* in_sizes, int n_in,
                              void* d_out, int out_size, void* d_ws, size_t ws_size,
                              hipStream_t stream) {
    const int* edge = (const int*)d_in[0];
    const int* row = edge;        // edge_index[0]
    const int* col = edge + NE;   // edge_index[1]
    const float* emb = (const float*)d_in[1];
    float* out = (float*)d_out;

    // workspace layout (ints, 64-aligned chunks)
    int* deg    = (int*)d_ws;          // 50000 (padded 50048)
    int* cursor = deg + 50048;         // 50000 (padded 50048)
    int* offs   = cursor + 50048;      // 50001 (padded 50112)
    int* partial= offs + 50112;        // 256
    int* csr    = partial + 256;       // 1250000 (padded 1250048)
    float* xa   = (float*)(csr + 1250048);  // 3.2M floats
    float* xb   = xa + NN * DIM;            // 3.2M floats
    // total ~31.2 MB

    hipMemsetAsync(deg, 0, (50048 + 50048) * sizeof(int), stream);  // deg + cursor

    k_count     <<<CBLOCKS, 256, 0, stream>>>(row, deg);
    k_scan_part <<<NPARTS, 256, 0, stream>>>(deg, partial);
    k_scan_top  <<<1, 256, 0, stream>>>(partial);
    k_scan_final<<<NPARTS, 256, 0, stream>>>(deg, partial, offs);
    k_fill      <<<NSLICES * 8, 256, 0, stream>>>(row, col, offs, cursor, csr);

    int layer_blocks = (NN * 64) / 256;  // 12500
    k_layer<true> <<<layer_blocks, 256, 0, stream>>>(emb, xa, out, offs, csr);
    k_layer<false><<<layer_blocks, 256, 0, stream>>>(xa,  xb, out, offs, csr);
    k_layer<false><<<layer_blocks, 256, 0, stream>>>(xb,  xa, out, offs, csr);
}

// Round 10
// 256.791 us; speedup vs baseline: 1.1389x; 1.0655x over previous
//
#include <hip/hip_runtime.h>

#define NN 50000
#define DIM 64
#define NE 1250000
#define NPARTS 196  // ceil(50000/256)

// ---- k_count config: 1280 blocks * 256 thr * U=4 = 1.31M slots >= NE
#define CBLOCKS 1280
#define CTHREADS (CBLOCKS * 256)
#define CU 4

// ---- k_fill config: 256 edge-slices x 8 row-ranges = 2048 blocks.
#define NSLICES 256
#define SLICE 4883            // ceil(NE / NSLICES)
#define RANGE 6250            // NN / 8 rows per XCD

// bf16 helpers (RNE pack, cheap unpack)
__device__ __forceinline__ unsigned short f2b(float f) {
    unsigned int b = __builtin_bit_cast(unsigned int, f);
    b = (b + 0x7fffu + ((b >> 16) & 1u)) >> 16;
    return (unsigned short)b;
}
__device__ __forceinline__ float b2f(unsigned short u) {
    return __builtin_bit_cast(float, (unsigned int)u << 16);
}

// ---------------- degree count ----------------
__global__ __launch_bounds__(256) void k_count(const int* __restrict__ row,
                                               int* __restrict__ deg) {
    int tid = blockIdx.x * blockDim.x + threadIdx.x;
    int r[CU];
#pragma unroll
    for (int k = 0; k < CU; ++k) {
        int e = tid + k * CTHREADS;
        r[k] = (e < NE) ? row[e] : -1;
    }
#pragma unroll
    for (int k = 0; k < CU; ++k)
        if (r[k] >= 0) atomicAdd(&deg[r[k]], 1);
}

// ---------------- fp32 -> bf16 pack of the embedding table ----------------
__global__ __launch_bounds__(256) void k_cvt(const float* __restrict__ in,
                                             unsigned short* __restrict__ out) {
    int t = blockIdx.x * blockDim.x + threadIdx.x;  // 8 elems per thread
    if (t >= NN * DIM / 8) return;
    const float4* p = (const float4*)in + t * 2;
    float4 a = p[0], b = p[1];
    ushort4 u0 = {f2b(a.x), f2b(a.y), f2b(a.z), f2b(a.w)};
    ushort4 u1 = {f2b(b.x), f2b(b.y), f2b(b.z), f2b(b.w)};
    ((ushort4*)out)[t * 2 + 0] = u0;
    ((ushort4*)out)[t * 2 + 1] = u1;
}

// ---------------- hierarchical exclusive scan over deg -> offs ----------------
__global__ __launch_bounds__(256) void k_scan_part(const int* __restrict__ deg,
                                                   int* __restrict__ partial) {
    __shared__ int s[256];
    int t = threadIdx.x;
    int i = blockIdx.x * 256 + t;
    s[t] = (i < NN) ? deg[i] : 0;
    __syncthreads();
    for (int off = 128; off > 0; off >>= 1) {
        if (t < off) s[t] += s[t + off];
        __syncthreads();
    }
    if (t == 0) partial[blockIdx.x] = s[0];
}

__global__ __launch_bounds__(256) void k_scan_top(int* __restrict__ partial) {
    __shared__ int s[256];
    int t = threadIdx.x;
    int v = (t < NPARTS) ? partial[t] : 0;
    s[t] = v;
    __syncthreads();
    for (int off = 1; off < 256; off <<= 1) {
        int x = (t >= off) ? s[t - off] : 0;
        __syncthreads();
        s[t] += x;
        __syncthreads();
    }
    if (t < NPARTS) partial[t] = s[t] - v;
}

__global__ __launch_bounds__(256) void k_scan_final(const int* __restrict__ deg,
                                                    const int* __restrict__ partial,
                                                    int* __restrict__ offs) {
    __shared__ int s[256];
    int t = threadIdx.x;
    int i = blockIdx.x * 256 + t;
    int v = (i < NN) ? deg[i] : 0;
    s[t] = v;
    __syncthreads();
    for (int off = 1; off < 256; off <<= 1) {
        int x = (t >= off) ? s[t - off] : 0;
        __syncthreads();
        s[t] += x;
        __syncthreads();
    }
    int excl = s[t] - v;
    if (i <= NN) offs[i] = partial[blockIdx.x] + excl;  // offs[NN] = NE
}

// ---------------- CSR fill, XCD-partitioned by row range ----------------
__global__ __launch_bounds__(256) void k_fill(const int* __restrict__ row,
                                              const int* __restrict__ col,
                                              const int* __restrict__ offs,
                                              int* __restrict__ cursor,
                                              int* __restrict__ csr) {
    int slice = blockIdx.x >> 3;
    int lo = (blockIdx.x & 7) * RANGE;
    int hi = lo + RANGE;
    int beg = slice * SLICE;
    int end = beg + SLICE;
    if (end > NE) end = NE;
    for (int e = beg + threadIdx.x; e < end; e += 256) {
        int r = row[e];
        if (r >= lo && r < hi) {
            int pos = offs[r] + atomicAdd(&cursor[r], 1);
            csr[pos] = col[e];
        }
    }
}

// ---------------- one propagation layer (bf16 gather, fp32 accum) ----------------
// x_new[r] = (1/deg[r]) * sum_{e in CSR[r]} x[col[e]]
// one 64-lane wave per node, lane = feature dim, 8-wide MLP unroll.
// PHASE 0: also out = 0.25*(emb + v)   (emb read fp32)
// PHASE 1: out += 0.25*v, store xout16
// PHASE 2: out += 0.25*v, no x store (last layer)
template <int PHASE>
__global__ __launch_bounds__(256) void k_layer(const unsigned short* __restrict__ xin16,
                                               const float* __restrict__ emb,
                                               unsigned short* __restrict__ xout16,
                                               float* __restrict__ out,
                                               const int* __restrict__ offs,
                                               const int* __restrict__ csr) {
    int wave = (blockIdx.x * blockDim.x + threadIdx.x) >> 6;
    int lane = threadIdx.x & 63;
    if (wave >= NN) return;
    int beg = offs[wave];
    int end = offs[wave + 1];
    const unsigned short* xl = xin16 + lane;

    float a0 = 0.f, a1 = 0.f, a2 = 0.f, a3 = 0.f;
    int e = beg;
    for (; e + 8 <= end; e += 8) {
        int c0 = csr[e + 0], c1 = csr[e + 1], c2 = csr[e + 2], c3 = csr[e + 3];
        int c4 = csr[e + 4], c5 = csr[e + 5], c6 = csr[e + 6], c7 = csr[e + 7];
        unsigned short u0 = xl[c0 * DIM];
        unsigned short u1 = xl[c1 * DIM];
        unsigned short u2 = xl[c2 * DIM];
        unsigned short u3 = xl[c3 * DIM];
        unsigned short u4 = xl[c4 * DIM];
        unsigned short u5 = xl[c5 * DIM];
        unsigned short u6 = xl[c6 * DIM];
        unsigned short u7 = xl[c7 * DIM];
        a0 += b2f(u0) + b2f(u4);
        a1 += b2f(u1) + b2f(u5);
        a2 += b2f(u2) + b2f(u6);
        a3 += b2f(u3) + b2f(u7);
    }
    for (; e < end; ++e) a0 += b2f(xl[csr[e] * DIM]);

    float acc = (a0 + a1) + (a2 + a3);
    int d = end - beg;
    float v = (d > 0) ? acc / (float)d : 0.0f;

    int o = wave * DIM + lane;
    if (PHASE == 0) {
        out[o] = 0.25f * (emb[o] + v);
        xout16[o] = f2b(v);
    } else if (PHASE == 1) {
        out[o] += 0.25f * v;
        xout16[o] = f2b(v);
    } else {
        out[o] += 0.25f * v;
    }
}

extern "C" void kernel_launch(void* const* d_in, const int* in_sizes, int n_in,
                              void* d_out, int out_size, void* d_ws, size_t ws_size,
                              hipStream_t stream) {
    const int* edge = (const int*)d_in[0];
    const int* row = edge;        // edge_index[0]
    const int* col = edge + NE;   // edge_index[1]
    const float* emb = (const float*)d_in[1];
    float* out = (float*)d_out;

    // workspace layout
    int* deg    = (int*)d_ws;          // 50048
    int* cursor = deg + 50048;         // 50048
    int* offs   = cursor + 50048;      // 50112
    int* partial= offs + 50112;        // 256
    int* csr    = partial + 256;       // 1250048
    unsigned short* x0 = (unsigned short*)(csr + 1250048);  // emb bf16, 3.2M ushort
    unsigned short* xa = x0 + NN * DIM;                     // 3.2M ushort
    unsigned short* xb = xa + NN * DIM;                     // 3.2M ushort
    // total ~25 MB

    hipMemsetAsync(deg, 0, (50048 + 50048) * sizeof(int), stream);  // deg + cursor

    k_count     <<<CBLOCKS, 256, 0, stream>>>(row, deg);
    k_cvt       <<<(NN * DIM / 8 + 255) / 256, 256, 0, stream>>>(emb, x0);
    k_scan_part <<<NPARTS, 256, 0, stream>>>(deg, partial);
    k_scan_top  <<<1, 256, 0, stream>>>(partial);
    k_scan_final<<<NPARTS, 256, 0, stream>>>(deg, partial, offs);
    k_fill      <<<NSLICES * 8, 256, 0, stream>>>(row, col, offs, cursor, csr);

    int layer_blocks = (NN * 64) / 256;  // 12500
    k_layer<0><<<layer_blocks, 256, 0, stream>>>(x0, emb, xa, out, offs, csr);
    k_layer<1><<<layer_blocks, 256, 0, stream>>>(xa, nullptr, xb, out, offs, csr);
    k_layer<2><<<layer_blocks, 256, 0, stream>>>(xb, nullptr, nullptr, out, offs, csr);
}

// Round 11
// 222.367 us; speedup vs baseline: 1.3152x; 1.1548x over previous
//
#include <hip/hip_runtime.h>

#define NN 50000
#define DIM 64
#define NE 1250000
#define NPARTS 196  // ceil(50000/256)

// ---- k_count config: 1280 blocks * 256 thr * U=4 = 1.31M slots >= NE
#define CBLOCKS 1280
#define CTHREADS (CBLOCKS * 256)
#define CU 4

// ---- k_fill config: 256 edge-slices x 8 row-ranges = 2048 blocks.
#define NSLICES 256
#define SLICE 4883            // ceil(NE / NSLICES)
#define RANGE 6250            // NN / 8 rows per XCD

// bf16 helpers (RNE pack, cheap unpack)
__device__ __forceinline__ unsigned short f2b(float f) {
    unsigned int b = __builtin_bit_cast(unsigned int, f);
    b = (b + 0x7fffu + ((b >> 16) & 1u)) >> 16;
    return (unsigned short)b;
}
__device__ __forceinline__ float b2f(unsigned short u) {
    return __builtin_bit_cast(float, (unsigned int)u << 16);
}
__device__ __forceinline__ float blo(unsigned int u) {
    return __builtin_bit_cast(float, u << 16);
}
__device__ __forceinline__ float bhi(unsigned int u) {
    return __builtin_bit_cast(float, u & 0xffff0000u);
}

// ---------------- degree count ----------------
__global__ __launch_bounds__(256) void k_count(const int* __restrict__ row,
                                               int* __restrict__ deg) {
    int tid = blockIdx.x * blockDim.x + threadIdx.x;
    int r[CU];
#pragma unroll
    for (int k = 0; k < CU; ++k) {
        int e = tid + k * CTHREADS;
        r[k] = (e < NE) ? row[e] : -1;
    }
#pragma unroll
    for (int k = 0; k < CU; ++k)
        if (r[k] >= 0) atomicAdd(&deg[r[k]], 1);
}

// ---------------- fp32 -> bf16 pack of the embedding table ----------------
__global__ __launch_bounds__(256) void k_cvt(const float* __restrict__ in,
                                             unsigned short* __restrict__ out) {
    int t = blockIdx.x * blockDim.x + threadIdx.x;  // 8 elems per thread
    if (t >= NN * DIM / 8) return;
    const float4* p = (const float4*)in + t * 2;
    float4 a = p[0], b = p[1];
    ushort4 u0 = {f2b(a.x), f2b(a.y), f2b(a.z), f2b(a.w)};
    ushort4 u1 = {f2b(b.x), f2b(b.y), f2b(b.z), f2b(b.w)};
    ((ushort4*)out)[t * 2 + 0] = u0;
    ((ushort4*)out)[t * 2 + 1] = u1;
}

// ---------------- hierarchical exclusive scan over deg -> offs ----------------
__global__ __launch_bounds__(256) void k_scan_part(const int* __restrict__ deg,
                                                   int* __restrict__ partial) {
    __shared__ int s[256];
    int t = threadIdx.x;
    int i = blockIdx.x * 256 + t;
    s[t] = (i < NN) ? deg[i] : 0;
    __syncthreads();
    for (int off = 128; off > 0; off >>= 1) {
        if (t < off) s[t] += s[t + off];
        __syncthreads();
    }
    if (t == 0) partial[blockIdx.x] = s[0];
}

__global__ __launch_bounds__(256) void k_scan_top(int* __restrict__ partial) {
    __shared__ int s[256];
    int t = threadIdx.x;
    int v = (t < NPARTS) ? partial[t] : 0;
    s[t] = v;
    __syncthreads();
    for (int off = 1; off < 256; off <<= 1) {
        int x = (t >= off) ? s[t - off] : 0;
        __syncthreads();
        s[t] += x;
        __syncthreads();
    }
    if (t < NPARTS) partial[t] = s[t] - v;
}

__global__ __launch_bounds__(256) void k_scan_final(const int* __restrict__ deg,
                                                    const int* __restrict__ partial,
                                                    int* __restrict__ offs) {
    __shared__ int s[256];
    int t = threadIdx.x;
    int i = blockIdx.x * 256 + t;
    int v = (i < NN) ? deg[i] : 0;
    s[t] = v;
    __syncthreads();
    for (int off = 1; off < 256; off <<= 1) {
        int x = (t >= off) ? s[t - off] : 0;
        __syncthreads();
        s[t] += x;
        __syncthreads();
    }
    int excl = s[t] - v;
    if (i <= NN) offs[i] = partial[blockIdx.x] + excl;  // offs[NN] = NE
}

// ---------------- CSR fill, XCD-partitioned by row range ----------------
__global__ __launch_bounds__(256) void k_fill(const int* __restrict__ row,
                                              const int* __restrict__ col,
                                              const int* __restrict__ offs,
                                              int* __restrict__ cursor,
                                              int* __restrict__ csr) {
    int slice = blockIdx.x >> 3;
    int lo = (blockIdx.x & 7) * RANGE;
    int hi = lo + RANGE;
    int beg = slice * SLICE;
    int end = beg + SLICE;
    if (end > NE) end = NE;
    for (int e = beg + threadIdx.x; e < end; e += 256) {
        int r = row[e];
        if (r >= lo && r < hi) {
            int pos = offs[r] + atomicAdd(&cursor[r], 1);
            csr[pos] = col[e];
        }
    }
}

// ---------------- one propagation layer (bf16 gather, fp32 accum) ----------------
// 2 nodes per wave: lanes 0-31 -> node 2w, lanes 32-63 -> node 2w+1.
// Each lane owns a FEATURE PAIR (2*sl, 2*sl+1) and loads one uint (2 bf16)
// -> one vector-mem instruction fetches 2 rows (256 B) instead of 1 (128 B),
// halving the wave-gather instruction count (layers are issue-rate-bound).
// PHASE 0: out = 0.25*(emb + v), store x16     (first layer, emb fp32 in)
// PHASE 1: out += 0.25*v, store x16
// PHASE 2: out += 0.25*v                       (last layer, no x store)
template <int PHASE>
__global__ __launch_bounds__(256) void k_layer(const unsigned short* __restrict__ xin16,
                                               const float* __restrict__ emb,
                                               unsigned short* __restrict__ xout16,
                                               float* __restrict__ out,
                                               const int* __restrict__ offs,
                                               const int* __restrict__ csr) {
    int wid = (blockIdx.x * blockDim.x + threadIdx.x) >> 6;
    int lane = threadIdx.x & 63;
    int half = lane >> 5;   // which node in this wave
    int sl = lane & 31;     // feature-pair index
    int n = 2 * wid + half;
    if (n >= NN) return;
    int beg = offs[n];
    int end = offs[n + 1];
    const unsigned short* xb = xin16 + sl * 2;  // +c*DIM per neighbor, 4B-aligned

    float p0 = 0.f, p1 = 0.f, p2 = 0.f, p3 = 0.f;  // even-feature partials
    float q0 = 0.f, q1 = 0.f, q2 = 0.f, q3 = 0.f;  // odd-feature partials
    int e = beg;
    for (; e + 8 <= end; e += 8) {
        int c0 = csr[e + 0], c1 = csr[e + 1], c2 = csr[e + 2], c3 = csr[e + 3];
        int c4 = csr[e + 4], c5 = csr[e + 5], c6 = csr[e + 6], c7 = csr[e + 7];
        unsigned int u0 = *(const unsigned int*)(xb + c0 * DIM);
        unsigned int u1 = *(const unsigned int*)(xb + c1 * DIM);
        unsigned int u2 = *(const unsigned int*)(xb + c2 * DIM);
        unsigned int u3 = *(const unsigned int*)(xb + c3 * DIM);
        unsigned int u4 = *(const unsigned int*)(xb + c4 * DIM);
        unsigned int u5 = *(const unsigned int*)(xb + c5 * DIM);
        unsigned int u6 = *(const unsigned int*)(xb + c6 * DIM);
        unsigned int u7 = *(const unsigned int*)(xb + c7 * DIM);
        p0 += blo(u0) + blo(u4);
        p1 += blo(u1) + blo(u5);
        p2 += blo(u2) + blo(u6);
        p3 += blo(u3) + blo(u7);
        q0 += bhi(u0) + bhi(u4);
        q1 += bhi(u1) + bhi(u5);
        q2 += bhi(u2) + bhi(u6);
        q3 += bhi(u3) + bhi(u7);
    }
    for (; e < end; ++e) {
        unsigned int u = *(const unsigned int*)(xb + csr[e] * DIM);
        p0 += blo(u);
        q0 += bhi(u);
    }

    float accLo = (p0 + p1) + (p2 + p3);
    float accHi = (q0 + q1) + (q2 + q3);
    int d = end - beg;
    float inv = (d > 0) ? 1.0f / (float)d : 0.0f;
    float v0 = accLo * inv;
    float v1 = accHi * inv;

    int o = n * DIM + sl * 2;
    if (PHASE == 0) {
        float2 ev = *(const float2*)(emb + o);
        float2 ov = {0.25f * (ev.x + v0), 0.25f * (ev.y + v1)};
        *(float2*)(out + o) = ov;
        unsigned int pk = (unsigned int)f2b(v0) | ((unsigned int)f2b(v1) << 16);
        *(unsigned int*)(xout16 + o) = pk;
    } else if (PHASE == 1) {
        float2 cur = *(const float2*)(out + o);
        cur.x += 0.25f * v0;
        cur.y += 0.25f * v1;
        *(float2*)(out + o) = cur;
        unsigned int pk = (unsigned int)f2b(v0) | ((unsigned int)f2b(v1) << 16);
        *(unsigned int*)(xout16 + o) = pk;
    } else {
        float2 cur = *(const float2*)(out + o);
        cur.x += 0.25f * v0;
        cur.y += 0.25f * v1;
        *(float2*)(out + o) = cur;
    }
}

extern "C" void kernel_launch(void* const* d_in, const int* in_sizes, int n_in,
                              void* d_out, int out_size, void* d_ws, size_t ws_size,
                              hipStream_t stream) {
    const int* edge = (const int*)d_in[0];
    const int* row = edge;        // edge_index[0]
    const int* col = edge + NE;   // edge_index[1]
    const float* emb = (const float*)d_in[1];
    float* out = (float*)d_out;

    // workspace layout
    int* deg    = (int*)d_ws;          // 50048
    int* cursor = deg + 50048;         // 50048
    int* offs   = cursor + 50048;      // 50112
    int* partial= offs + 50112;        // 256
    int* csr    = partial + 256;       // 1250048
    unsigned short* x0 = (unsigned short*)(csr + 1250048);  // emb bf16
    unsigned short* xa = x0 + NN * DIM;
    unsigned short* xb = xa + NN * DIM;
    // total ~25 MB

    hipMemsetAsync(deg, 0, (50048 + 50048) * sizeof(int), stream);  // deg + cursor

    k_count     <<<CBLOCKS, 256, 0, stream>>>(row, deg);
    k_cvt       <<<(NN * DIM / 8 + 255) / 256, 256, 0, stream>>>(emb, x0);
    k_scan_part <<<NPARTS, 256, 0, stream>>>(deg, partial);
    k_scan_top  <<<1, 256, 0, stream>>>(partial);
    k_scan_final<<<NPARTS, 256, 0, stream>>>(deg, partial, offs);
    k_fill      <<<NSLICES * 8, 256, 0, stream>>>(row, col, offs, cursor, csr);

    // 2 nodes per wave: 25000 waves -> 6250 blocks of 256
    int layer_blocks = (NN / 2 * 64) / 256;  // 6250
    k_layer<0><<<layer_blocks, 256, 0, stream>>>(x0, emb, xa, out, offs, csr);
    k_layer<1><<<layer_blocks, 256, 0, stream>>>(xa, nullptr, xb, out, offs, csr);
    k_layer<2><<<layer_blocks, 256, 0, stream>>>(xb, nullptr, nullptr, out, offs, csr);
}

// Round 12
// 214.141 us; speedup vs baseline: 1.3657x; 1.0384x over previous
//
#include <hip/hip_runtime.h>

#define NN 50000
#define DIM 64
#define NE 1250000
#define NPARTS 196  // ceil(50000/256)

// ---- k_count config: 1280 blocks * 256 thr * U=4 = 1.31M slots >= NE
#define CBLOCKS 1280
#define CTHREADS (CBLOCKS * 256)
#define CU 4

// ---- k_fill config: 256 edge-slices x 8 row-ranges = 2048 blocks.
#define NSLICES 256
#define SLICE 4883            // ceil(NE / NSLICES)
#define RANGE 6250            // NN / 8 rows per range

// bf16 helpers (RNE pack, cheap unpack)
__device__ __forceinline__ unsigned short f2b(float f) {
    unsigned int b = __builtin_bit_cast(unsigned int, f);
    b = (b + 0x7fffu + ((b >> 16) & 1u)) >> 16;
    return (unsigned short)b;
}
__device__ __forceinline__ float blo(unsigned int u) {
    return __builtin_bit_cast(float, u << 16);
}
__device__ __forceinline__ float bhi(unsigned int u) {
    return __builtin_bit_cast(float, u & 0xffff0000u);
}

// ---------------- degree count ----------------
__global__ __launch_bounds__(256) void k_count(const int* __restrict__ row,
                                               int* __restrict__ deg) {
    int tid = blockIdx.x * blockDim.x + threadIdx.x;
    int r[CU];
#pragma unroll
    for (int k = 0; k < CU; ++k) {
        int e = tid + k * CTHREADS;
        r[k] = (e < NE) ? row[e] : -1;
    }
#pragma unroll
    for (int k = 0; k < CU; ++k)
        if (r[k] >= 0) atomicAdd(&deg[r[k]], 1);
}

// ---------------- fp32 -> bf16 pack of the embedding table ----------------
__global__ __launch_bounds__(256) void k_cvt(const float* __restrict__ in,
                                             unsigned short* __restrict__ out) {
    int t = blockIdx.x * blockDim.x + threadIdx.x;  // 8 elems per thread
    if (t >= NN * DIM / 8) return;
    const float4* p = (const float4*)in + t * 2;
    float4 a = p[0], b = p[1];
    ushort4 u0 = {f2b(a.x), f2b(a.y), f2b(a.z), f2b(a.w)};
    ushort4 u1 = {f2b(b.x), f2b(b.y), f2b(b.z), f2b(b.w)};
    ((ushort4*)out)[t * 2 + 0] = u0;
    ((ushort4*)out)[t * 2 + 1] = u1;
}

// ---------------- hierarchical exclusive scan over deg -> offs ----------------
__global__ __launch_bounds__(256) void k_scan_part(const int* __restrict__ deg,
                                                   int* __restrict__ partial) {
    __shared__ int s[256];
    int t = threadIdx.x;
    int i = blockIdx.x * 256 + t;
    s[t] = (i < NN) ? deg[i] : 0;
    __syncthreads();
    for (int off = 128; off > 0; off >>= 1) {
        if (t < off) s[t] += s[t + off];
        __syncthreads();
    }
    if (t == 0) partial[blockIdx.x] = s[0];
}

__global__ __launch_bounds__(256) void k_scan_top(int* __restrict__ partial) {
    __shared__ int s[256];
    int t = threadIdx.x;
    int v = (t < NPARTS) ? partial[t] : 0;
    s[t] = v;
    __syncthreads();
    for (int off = 1; off < 256; off <<= 1) {
        int x = (t >= off) ? s[t - off] : 0;
        __syncthreads();
        s[t] += x;
        __syncthreads();
    }
    if (t < NPARTS) partial[t] = s[t] - v;
}

__global__ __launch_bounds__(256) void k_scan_final(const int* __restrict__ deg,
                                                    const int* __restrict__ partial,
                                                    int* __restrict__ offs) {
    __shared__ int s[256];
    int t = threadIdx.x;
    int i = blockIdx.x * 256 + t;
    int v = (i < NN) ? deg[i] : 0;
    s[t] = v;
    __syncthreads();
    for (int off = 1; off < 256; off <<= 1) {
        int x = (t >= off) ? s[t - off] : 0;
        __syncthreads();
        s[t] += x;
        __syncthreads();
    }
    int excl = s[t] - v;
    if (i <= NN) offs[i] = partial[blockIdx.x] + excl;  // offs[NN] = NE
}

// ---------------- CSR fill, XCD-coscheduled slices ----------------
// (slice, range) -> bid = (s&7) + 8*(range + 8*(s>>3)): all 8 range-blocks
// of slice s satisfy bid%8 == s%8 -> same XCD (round-robin mapping), so the
// slice's row/col data is fetched into that XCD's L2 ONCE and the other 7
// passes hit L2. Bijective onto [0,2048). Correct under any XCD mapping.
__global__ __launch_bounds__(256) void k_fill(const int* __restrict__ row,
                                              const int* __restrict__ col,
                                              const int* __restrict__ offs,
                                              int* __restrict__ cursor,
                                              int* __restrict__ csr) {
    int bid = blockIdx.x;
    int slice = (bid & 7) | ((bid >> 6) << 3);
    int rng   = (bid >> 3) & 7;
    int lo = rng * RANGE;
    int hi = lo + RANGE;
    int beg = slice * SLICE;
    int end = beg + SLICE;
    if (end > NE) end = NE;
    for (int e = beg + threadIdx.x; e < end; e += 256) {
        int r = row[e];
        if (r >= lo && r < hi) {
            int pos = offs[r] + atomicAdd(&cursor[r], 1);
            csr[pos] = col[e];
        }
    }
}

// ---------------- one propagation layer (bf16 gather, fp32 accum) ----------------
// 4 nodes per wave: lane>>4 = node index within wave, lane&15 = feature-quad.
// Each lane loads uint2 (4 bf16, 8 B) -> one vector-mem instruction fetches
// 4 rows (512 B); wave-gather instruction count halves vs 2-node version
// (layers are issue-rate-bound, round-10/11 evidence).
// PHASE 0: out = 0.25*(emb + v), store x16     (first layer, emb fp32 in)
// PHASE 1: out += 0.25*v, store x16
// PHASE 2: out += 0.25*v                       (last layer, no x store)
template <int PHASE>
__global__ __launch_bounds__(256) void k_layer(const unsigned short* __restrict__ xin16,
                                               const float* __restrict__ emb,
                                               unsigned short* __restrict__ xout16,
                                               float* __restrict__ out,
                                               const int* __restrict__ offs,
                                               const int* __restrict__ csr) {
    int wid = (blockIdx.x * blockDim.x + threadIdx.x) >> 6;
    int lane = threadIdx.x & 63;
    int sub = lane >> 4;    // node within wave (0..3)
    int sl = lane & 15;     // feature-quad index (0..15)
    int n = 4 * wid + sub;
    if (n >= NN) return;
    int beg = offs[n];
    int end = offs[n + 1];
    const unsigned short* xq = xin16 + sl * 4;  // + c*DIM per neighbor, 8B-aligned

    // 8 accumulators: a_j/b_j for feature j of the quad
    float a0 = 0.f, a1 = 0.f, a2 = 0.f, a3 = 0.f;
    float b0 = 0.f, b1 = 0.f, b2 = 0.f, b3 = 0.f;
    int e = beg;
    for (; e + 8 <= end; e += 8) {
        int c0 = csr[e + 0], c1 = csr[e + 1], c2 = csr[e + 2], c3 = csr[e + 3];
        int c4 = csr[e + 4], c5 = csr[e + 5], c6 = csr[e + 6], c7 = csr[e + 7];
        uint2 u0 = *(const uint2*)(xq + c0 * DIM);
        uint2 u1 = *(const uint2*)(xq + c1 * DIM);
        uint2 u2 = *(const uint2*)(xq + c2 * DIM);
        uint2 u3 = *(const uint2*)(xq + c3 * DIM);
        uint2 u4 = *(const uint2*)(xq + c4 * DIM);
        uint2 u5 = *(const uint2*)(xq + c5 * DIM);
        uint2 u6 = *(const uint2*)(xq + c6 * DIM);
        uint2 u7 = *(const uint2*)(xq + c7 * DIM);
        a0 += blo(u0.x) + blo(u4.x);  b0 += blo(u1.x) + blo(u5.x);
        a1 += bhi(u0.x) + bhi(u4.x);  b1 += bhi(u1.x) + bhi(u5.x);
        a2 += blo(u0.y) + blo(u4.y);  b2 += blo(u1.y) + blo(u5.y);
        a3 += bhi(u0.y) + bhi(u4.y);  b3 += bhi(u1.y) + bhi(u5.y);
        a0 += blo(u2.x) + blo(u6.x);  b0 += blo(u3.x) + blo(u7.x);
        a1 += bhi(u2.x) + bhi(u6.x);  b1 += bhi(u3.x) + bhi(u7.x);
        a2 += blo(u2.y) + blo(u6.y);  b2 += blo(u3.y) + blo(u7.y);
        a3 += bhi(u2.y) + bhi(u6.y);  b3 += bhi(u3.y) + bhi(u7.y);
    }
    for (; e < end; ++e) {
        uint2 u = *(const uint2*)(xq + csr[e] * DIM);
        a0 += blo(u.x);
        a1 += bhi(u.x);
        a2 += blo(u.y);
        a3 += bhi(u.y);
    }

    int d = end - beg;
    float inv = (d > 0) ? 1.0f / (float)d : 0.0f;
    float v0 = (a0 + b0) * inv;
    float v1 = (a1 + b1) * inv;
    float v2 = (a2 + b2) * inv;
    float v3 = (a3 + b3) * inv;

    int o = n * DIM + sl * 4;
    if (PHASE == 0) {
        float4 ev = *(const float4*)(emb + o);
        float4 ov = {0.25f * (ev.x + v0), 0.25f * (ev.y + v1),
                     0.25f * (ev.z + v2), 0.25f * (ev.w + v3)};
        *(float4*)(out + o) = ov;
        uint2 pk = {(unsigned int)f2b(v0) | ((unsigned int)f2b(v1) << 16),
                    (unsigned int)f2b(v2) | ((unsigned int)f2b(v3) << 16)};
        *(uint2*)(xout16 + o) = pk;
    } else if (PHASE == 1) {
        float4 cur = *(const float4*)(out + o);
        cur.x += 0.25f * v0;
        cur.y += 0.25f * v1;
        cur.z += 0.25f * v2;
        cur.w += 0.25f * v3;
        *(float4*)(out + o) = cur;
        uint2 pk = {(unsigned int)f2b(v0) | ((unsigned int)f2b(v1) << 16),
                    (unsigned int)f2b(v2) | ((unsigned int)f2b(v3) << 16)};
        *(uint2*)(xout16 + o) = pk;
    } else {
        float4 cur = *(const float4*)(out + o);
        cur.x += 0.25f * v0;
        cur.y += 0.25f * v1;
        cur.z += 0.25f * v2;
        cur.w += 0.25f * v3;
        *(float4*)(out + o) = cur;
    }
}

extern "C" void kernel_launch(void* const* d_in, const int* in_sizes, int n_in,
                              void* d_out, int out_size, void* d_ws, size_t ws_size,
                              hipStream_t stream) {
    const int* edge = (const int*)d_in[0];
    const int* row = edge;        // edge_index[0]
    const int* col = edge + NE;   // edge_index[1]
    const float* emb = (const float*)d_in[1];
    float* out = (float*)d_out;

    // workspace layout
    int* deg    = (int*)d_ws;          // 50048
    int* cursor = deg + 50048;         // 50048
    int* offs   = cursor + 50048;      // 50112
    int* partial= offs + 50112;        // 256
    int* csr    = partial + 256;       // 1250048
    unsigned short* x0 = (unsigned short*)(csr + 1250048);  // emb bf16
    unsigned short* xa = x0 + NN * DIM;
    unsigned short* xb = xa + NN * DIM;
    // total ~25 MB

    hipMemsetAsync(deg, 0, (50048 + 50048) * sizeof(int), stream);  // deg + cursor

    k_count     <<<CBLOCKS, 256, 0, stream>>>(row, deg);
    k_cvt       <<<(NN * DIM / 8 + 255) / 256, 256, 0, stream>>>(emb, x0);
    k_scan_part <<<NPARTS, 256, 0, stream>>>(deg, partial);
    k_scan_top  <<<1, 256, 0, stream>>>(partial);
    k_scan_final<<<NPARTS, 256, 0, stream>>>(deg, partial, offs);
    k_fill      <<<NSLICES * 8, 256, 0, stream>>>(row, col, offs, cursor, csr);

    // 4 nodes per wave: 12500 waves -> 3125 blocks of 256
    int layer_blocks = (NN / 4 * 64) / 256;  // 3125
    k_layer<0><<<layer_blocks, 256, 0, stream>>>(x0, emb, xa, out, offs, csr);
    k_layer<1><<<layer_blocks, 256, 0, stream>>>(xa, nullptr, xb, out, offs, csr);
    k_layer<2><<<layer_blocks, 256, 0, stream>>>(xb, nullptr, nullptr, out, offs, csr);
}

// Round 13
// 145.681 us; speedup vs baseline: 2.0075x; 1.4699x over previous
//
#include <hip/hip_runtime.h>

#define NN 50000
#define DIM 64
#define NE 1250000
#define NPARTS 196  // ceil(50000/256)

// ---- counting-sort CSR build: 64 edge-slices x 8 row-ranges ----
#define NSL 64
#define SLICEB 19532          // ceil(NE / NSL)
#define RANGE 6250            // NN / 8 rows per range
#define CSTRIDE 50048         // padded row stride of cnt matrix

// bf16 helpers (RNE pack, cheap unpack)
__device__ __forceinline__ unsigned short f2b(float f) {
    unsigned int b = __builtin_bit_cast(unsigned int, f);
    b = (b + 0x7fffu + ((b >> 16) & 1u)) >> 16;
    return (unsigned short)b;
}
__device__ __forceinline__ float blo(unsigned int u) {
    return __builtin_bit_cast(float, u << 16);
}
__device__ __forceinline__ float bhi(unsigned int u) {
    return __builtin_bit_cast(float, u & 0xffff0000u);
}

// ---------------- fp32 -> bf16 pack of the embedding table ----------------
__global__ __launch_bounds__(256) void k_cvt(const float* __restrict__ in,
                                             unsigned short* __restrict__ out) {
    int t = blockIdx.x * blockDim.x + threadIdx.x;  // 8 elems per thread
    if (t >= NN * DIM / 8) return;
    const float4* p = (const float4*)in + t * 2;
    float4 a = p[0], b = p[1];
    ushort4 u0 = {f2b(a.x), f2b(a.y), f2b(a.z), f2b(a.w)};
    ushort4 u1 = {f2b(b.x), f2b(b.y), f2b(b.z), f2b(b.w)};
    ((ushort4*)out)[t * 2 + 0] = u0;
    ((ushort4*)out)[t * 2 + 1] = u1;
}

// ---------------- per-slice LDS histogram (NO global atomics) ----------------
// block bid -> slice s = (bid&7)|((bid>>6)<<3), range rng = (bid>>3)&7.
// bid%8 == s%8 -> all 8 range-blocks of a slice land on one XCD (L2 reuse).
__global__ __launch_bounds__(512) void k_hist(const int* __restrict__ row,
                                              unsigned short* __restrict__ cnt) {
    __shared__ int h[RANGE];
    int bid = blockIdx.x;
    int s   = (bid & 7) | ((bid >> 6) << 3);
    int rng = (bid >> 3) & 7;
    int lo = rng * RANGE;
    int tid = threadIdx.x;
    for (int i = tid; i < RANGE; i += 512) h[i] = 0;
    __syncthreads();
    int beg = s * SLICEB;
    int end = beg + SLICEB;
    if (end > NE) end = NE;
    for (int e = beg + tid; e < end; e += 512) {
        int r = row[e] - lo;
        if ((unsigned)r < RANGE) atomicAdd(&h[r], 1);  // LDS atomic
    }
    __syncthreads();
    unsigned short* c = cnt + s * CSTRIDE + lo;
    for (int i = tid; i < RANGE; i += 512) c[i] = (unsigned short)h[i];
}

// ---------------- per-row scan over slices: cnt -> rel offsets, deg ----------------
__global__ __launch_bounds__(256) void k_rowscan(unsigned short* __restrict__ cnt,
                                                 int* __restrict__ deg) {
    int r = blockIdx.x * blockDim.x + threadIdx.x;
    if (r >= NN) return;
    int acc = 0;
#pragma unroll
    for (int s = 0; s < NSL; ++s) {
        int c = cnt[s * CSTRIDE + r];
        cnt[s * CSTRIDE + r] = (unsigned short)acc;  // exclusive within-row offset
        acc += c;
    }
    deg[r] = acc;
}

// ---------------- hierarchical exclusive scan over deg -> offs ----------------
__global__ __launch_bounds__(256) void k_scan_part(const int* __restrict__ deg,
                                                   int* __restrict__ partial) {
    __shared__ int s[256];
    int t = threadIdx.x;
    int i = blockIdx.x * 256 + t;
    s[t] = (i < NN) ? deg[i] : 0;
    __syncthreads();
    for (int off = 128; off > 0; off >>= 1) {
        if (t < off) s[t] += s[t + off];
        __syncthreads();
    }
    if (t == 0) partial[blockIdx.x] = s[0];
}

__global__ __launch_bounds__(256) void k_scan_top(int* __restrict__ partial) {
    __shared__ int s[256];
    int t = threadIdx.x;
    int v = (t < NPARTS) ? partial[t] : 0;
    s[t] = v;
    __syncthreads();
    for (int off = 1; off < 256; off <<= 1) {
        int x = (t >= off) ? s[t - off] : 0;
        __syncthreads();
        s[t] += x;
        __syncthreads();
    }
    if (t < NPARTS) partial[t] = s[t] - v;
}

__global__ __launch_bounds__(256) void k_scan_final(const int* __restrict__ deg,
                                                    const int* __restrict__ partial,
                                                    int* __restrict__ offs) {
    __shared__ int s[256];
    int t = threadIdx.x;
    int i = blockIdx.x * 256 + t;
    int v = (i < NN) ? deg[i] : 0;
    s[t] = v;
    __syncthreads();
    for (int off = 1; off < 256; off <<= 1) {
        int x = (t >= off) ? s[t - off] : 0;
        __syncthreads();
        s[t] += x;
        __syncthreads();
    }
    int excl = s[t] - v;
    if (i <= NN) offs[i] = partial[blockIdx.x] + excl;  // offs[NN] = NE
}

// ---------------- CSR fill via LDS cursor (NO global atomics) ----------------
__global__ __launch_bounds__(512) void k_fillb(const int* __restrict__ row,
                                               const int* __restrict__ col,
                                               const int* __restrict__ offs,
                                               const unsigned short* __restrict__ cnt,
                                               int* __restrict__ csr) {
    __shared__ int cur[RANGE];
    int bid = blockIdx.x;
    int s   = (bid & 7) | ((bid >> 6) << 3);
    int rng = (bid >> 3) & 7;
    int lo = rng * RANGE;
    int tid = threadIdx.x;
    const unsigned short* c = cnt + s * CSTRIDE + lo;
    const int* o = offs + lo;
    for (int i = tid; i < RANGE; i += 512) cur[i] = o[i] + c[i];
    __syncthreads();
    int beg = s * SLICEB;
    int end = beg + SLICEB;
    if (end > NE) end = NE;
    for (int e = beg + tid; e < end; e += 512) {
        int r = row[e] - lo;
        if ((unsigned)r < RANGE) {
            int pos = atomicAdd(&cur[r], 1);  // LDS atomic
            csr[pos] = col[e];
        }
    }
}

// ---------------- one propagation layer (bf16 gather, fp32 accum) ----------------
// 4 nodes per wave: lane>>4 = node in wave, lane&15 = feature-quad (uint2 load).
template <int PHASE>
__global__ __launch_bounds__(256) void k_layer(const unsigned short* __restrict__ xin16,
                                               const float* __restrict__ emb,
                                               unsigned short* __restrict__ xout16,
                                               float* __restrict__ out,
                                               const int* __restrict__ offs,
                                               const int* __restrict__ csr) {
    int wid = (blockIdx.x * blockDim.x + threadIdx.x) >> 6;
    int lane = threadIdx.x & 63;
    int sub = lane >> 4;    // node within wave (0..3)
    int sl = lane & 15;     // feature-quad index (0..15)
    int n = 4 * wid + sub;
    if (n >= NN) return;
    int beg = offs[n];
    int end = offs[n + 1];
    const unsigned short* xq = xin16 + sl * 4;

    float a0 = 0.f, a1 = 0.f, a2 = 0.f, a3 = 0.f;
    float b0 = 0.f, b1 = 0.f, b2 = 0.f, b3 = 0.f;
    int e = beg;
    for (; e + 8 <= end; e += 8) {
        int c0 = csr[e + 0], c1 = csr[e + 1], c2 = csr[e + 2], c3 = csr[e + 3];
        int c4 = csr[e + 4], c5 = csr[e + 5], c6 = csr[e + 6], c7 = csr[e + 7];
        uint2 u0 = *(const uint2*)(xq + c0 * DIM);
        uint2 u1 = *(const uint2*)(xq + c1 * DIM);
        uint2 u2 = *(const uint2*)(xq + c2 * DIM);
        uint2 u3 = *(const uint2*)(xq + c3 * DIM);
        uint2 u4 = *(const uint2*)(xq + c4 * DIM);
        uint2 u5 = *(const uint2*)(xq + c5 * DIM);
        uint2 u6 = *(const uint2*)(xq + c6 * DIM);
        uint2 u7 = *(const uint2*)(xq + c7 * DIM);
        a0 += blo(u0.x) + blo(u4.x);  b0 += blo(u1.x) + blo(u5.x);
        a1 += bhi(u0.x) + bhi(u4.x);  b1 += bhi(u1.x) + bhi(u5.x);
        a2 += blo(u0.y) + blo(u4.y);  b2 += blo(u1.y) + blo(u5.y);
        a3 += bhi(u0.y) + bhi(u4.y);  b3 += bhi(u1.y) + bhi(u5.y);
        a0 += blo(u2.x) + blo(u6.x);  b0 += blo(u3.x) + blo(u7.x);
        a1 += bhi(u2.x) + bhi(u6.x);  b1 += bhi(u3.x) + bhi(u7.x);
        a2 += blo(u2.y) + blo(u6.y);  b2 += blo(u3.y) + blo(u7.y);
        a3 += bhi(u2.y) + bhi(u6.y);  b3 += bhi(u3.y) + bhi(u7.y);
    }
    for (; e < end; ++e) {
        uint2 u = *(const uint2*)(xq + csr[e] * DIM);
        a0 += blo(u.x);
        a1 += bhi(u.x);
        a2 += blo(u.y);
        a3 += bhi(u.y);
    }

    int d = end - beg;
    float inv = (d > 0) ? 1.0f / (float)d : 0.0f;
    float v0 = (a0 + b0) * inv;
    float v1 = (a1 + b1) * inv;
    float v2 = (a2 + b2) * inv;
    float v3 = (a3 + b3) * inv;

    int o = n * DIM + sl * 4;
    if (PHASE == 0) {
        float4 ev = *(const float4*)(emb + o);
        float4 ov = {0.25f * (ev.x + v0), 0.25f * (ev.y + v1),
                     0.25f * (ev.z + v2), 0.25f * (ev.w + v3)};
        *(float4*)(out + o) = ov;
        uint2 pk = {(unsigned int)f2b(v0) | ((unsigned int)f2b(v1) << 16),
                    (unsigned int)f2b(v2) | ((unsigned int)f2b(v3) << 16)};
        *(uint2*)(xout16 + o) = pk;
    } else if (PHASE == 1) {
        float4 cur = *(const float4*)(out + o);
        cur.x += 0.25f * v0;
        cur.y += 0.25f * v1;
        cur.z += 0.25f * v2;
        cur.w += 0.25f * v3;
        *(float4*)(out + o) = cur;
        uint2 pk = {(unsigned int)f2b(v0) | ((unsigned int)f2b(v1) << 16),
                    (unsigned int)f2b(v2) | ((unsigned int)f2b(v3) << 16)};
        *(uint2*)(xout16 + o) = pk;
    } else {
        float4 cur = *(const float4*)(out + o);
        cur.x += 0.25f * v0;
        cur.y += 0.25f * v1;
        cur.z += 0.25f * v2;
        cur.w += 0.25f * v3;
        *(float4*)(out + o) = cur;
    }
}

extern "C" void kernel_launch(void* const* d_in, const int* in_sizes, int n_in,
                              void* d_out, int out_size, void* d_ws, size_t ws_size,
                              hipStream_t stream) {
    const int* edge = (const int*)d_in[0];
    const int* row = edge;        // edge_index[0]
    const int* col = edge + NE;   // edge_index[1]
    const float* emb = (const float*)d_in[1];
    float* out = (float*)d_out;

    // workspace layout (~31 MB)
    int* deg    = (int*)d_ws;                                // 50048 ints
    int* offs   = deg + 50048;                               // 50112 ints
    int* partial= offs + 50112;                              // 256 ints
    int* csr    = partial + 256;                             // 1250048 ints
    unsigned short* cnt = (unsigned short*)(csr + 1250048);  // 64*50048 ushort (6.4MB)
    unsigned short* x0  = cnt + NSL * CSTRIDE;               // 3.2M ushort
    unsigned short* xa  = x0 + NN * DIM;
    unsigned short* xb  = xa + NN * DIM;

    k_cvt       <<<(NN * DIM / 8 + 255) / 256, 256, 0, stream>>>(emb, x0);
    k_hist      <<<NSL * 8, 512, 0, stream>>>(row, cnt);
    k_rowscan   <<<NPARTS, 256, 0, stream>>>(cnt, deg);
    k_scan_part <<<NPARTS, 256, 0, stream>>>(deg, partial);
    k_scan_top  <<<1, 256, 0, stream>>>(partial);
    k_scan_final<<<NPARTS, 256, 0, stream>>>(deg, partial, offs);
    k_fillb     <<<NSL * 8, 512, 0, stream>>>(row, col, offs, cnt, csr);

    // 4 nodes per wave: 12500 waves -> 3125 blocks of 256
    int layer_blocks = (NN / 4 * 64) / 256;  // 3125
    k_layer<0><<<layer_blocks, 256, 0, stream>>>(x0, emb, xa, out, offs, csr);
    k_layer<1><<<layer_blocks, 256, 0, stream>>>(xa, nullptr, xb, out, offs, csr);
    k_layer<2><<<layer_blocks, 256, 0, stream>>>(xb, nullptr, nullptr, out, offs, csr);
}